// Round 6
// baseline (244.926 us; speedup 1.0000x reference)
//
#include <hip/hip_runtime.h>

// CTC loss forward. logits (T,N,C) fp32 log-probs, labels (N,S) int32 in
// [1,C), prediction/target sizes (N,).
//
// R5 post-mortem: linear-space chain cut alpha 107->~70us, far above the
// ~11us chain floor. At 1 wave/SIMD every staging instruction (16 ds_read,
// 16 quarter-rate v_exp, 8 gather issues w/ 64-bit addr math, copies,
// renorm) is serialized onto the same wave as the recurrence. R6: wave
// specialization. Wave 1 (producer) owns the global_load_lds gather ring +
// exp()+mask + packs per-step (eb,el) float2 into a 64-step LDS emission
// ring. Wave 0 (consumer) does one ds_read_b64 + DPP + add/fma/mul per
// step. LDS spin-flag sync (volatile + manual lgkmcnt(0) release) -- no
// __syncthreads after init, so the producer's vmem queue never drains.
// Renorm every 16 steps (max growth e^64 ~ 6e27, inside fp32 range).

constexpr int T = 512, N = 256, C = 256, S = 48;
constexpr int RW = 64;                 // raw gather ring rows (+junk slot)
constexpr int RS = 64;                 // emission ring steps (8 groups)
constexpr int A  = 40;                 // producer issue-ahead rows (vmcnt imm!)
constexpr int G  = 8;                  // steps per group
constexpr int NG = 64;                 // 63 full groups + 1 partial (7 steps)
constexpr float BOOST = 4.0f;          // per-live-step emission boost (e^4)
static_assert(T == (NG - 1) * G + G, "schedule hardcodes 64 groups over t=1..512");

__device__ __forceinline__ float wave_shr1(float v, float fill) {
  int r = __builtin_amdgcn_update_dpp(__float_as_int(fill), __float_as_int(v),
                                      0x138, 0xf, 0xf, false);  // wave_shr1
  return __int_as_float(r);
}

#define DPP_MAX(v, ctrl)                                                     \
  fmaxf(v, __int_as_float(__builtin_amdgcn_update_dpp(                       \
               __float_as_int(v), __float_as_int(v), (ctrl), 0xf, 0xf, false)))

// max over 64 lanes, wave-uniform result (alpha >= 0, so old-value fallback
// on bcast-inactive lanes is safe).
__device__ __forceinline__ float wavemax(float v) {
  v = DPP_MAX(v, 0x111);               // row_shr:1
  v = DPP_MAX(v, 0x112);               // row_shr:2
  v = DPP_MAX(v, 0x114);               // row_shr:4
  v = DPP_MAX(v, 0x118);               // row_shr:8
  v = DPP_MAX(v, 0x142);               // row_bcast:15
  v = DPP_MAX(v, 0x143);               // row_bcast:31 -> lane 63 = full max
  return __int_as_float(__builtin_amdgcn_readlane(__float_as_int(v), 63));
}

// async global->LDS: per-lane 4B load, HW scatters to ldsbase + lane*4
__device__ __forceinline__ void gload_lds(const float* g, float* l) {
  __builtin_amdgcn_global_load_lds(
      (const __attribute__((address_space(1))) unsigned int*)g,
      (__attribute__((address_space(3))) unsigned int*)l, 4, 0, 0);
}

__launch_bounds__(128, 1)
__global__ void ctc_alpha_kernel(const float* __restrict__ lp,
                                 const int*  __restrict__ labels,
                                 const int*  __restrict__ in_len,
                                 const int*  __restrict__ tgt_len,
                                 float* __restrict__ loss_ws) {
  __shared__ float raw[(RW + 2) * 64]; // gather ring + junk slot + pad
  __shared__ float E[RS * 128];        // per-step packed (eb,el) per lane
  __shared__ int flagP, flagC;         // producer/consumer progress (group id)

  const int lane = threadIdx.x & 63;
  const int wv   = threadIdx.x >> 6;   // 0 = consumer, 1 = producer
  const int n    = blockIdx.x;

  if (threadIdx.x == 0) { flagP = -1; flagC = -1; }
  __syncthreads();                     // only barrier in the kernel

  volatile int* vP = &flagP;
  volatile int* vC = &flagC;

  const size_t stride = (size_t)N * C;           // row stride over t
  const float* base = lp + (size_t)n * C;        // lp[0][n][:]

  if (wv == 1) {
    // ------------------------- producer wave -------------------------
    const int glab = (lane >= 1 && lane <= S) ? labels[n * S + lane - 1] : 0;
    const bool v0 = (lane <= S), v1 = (lane < S);

    auto issue = [&](int row) {        // exactly one vmem inst per call
      const bool ok  = (row < T);
      const int slot = ok ? (row & (RW - 1)) : RW;
      const int rr   = ok ? row : (T - 1);
      gload_lds(base + (size_t)rr * stride + glab, &raw[slot * 64]);
    };

#pragma unroll
    for (int r = 1; r <= A; ++r) issue(r);       // prologue: rows 1..40

    int lastC = -1;
    int t0 = 1;
#pragma unroll 1
    for (int g = 0; g < NG; ++g, t0 += G) {
      // E-ring slot reuse (group g aliases g-8): wait consumer >= g-6.
      while (lastC < g - 6) lastC = *vC;
#pragma unroll
      for (int d = 0; d < G; ++d) issue(t0 + A + d);
      // outstanding 48 -> wait to 40: rows <= t0+7 resident.
      asm volatile("s_waitcnt vmcnt(40)" ::: "memory");
#pragma unroll
      for (int d = 0; d < G; ++d) {
        const int r = t0 + d;
        const int s = (r < T) ? (r & (RW - 1)) : RW;
        const float b = raw[s * 64];             // broadcast read
        const float l = raw[s * 64 + 1 + lane];
        float2 e;
        e.x = v0 ? __expf(b + BOOST) : 0.0f;     // blank emission, masked
        e.y = v1 ? __expf(l + BOOST) : 0.0f;     // label emission, masked
        *(float2*)&E[(r & (RS - 1)) * 128 + lane * 2] = e;
      }
      asm volatile("s_waitcnt lgkmcnt(0)" ::: "memory");  // release
      if (lane == 0) *vP = g;
    }
    return;
  }

  // ------------------------- consumer wave -------------------------
  const int lab      = (lane < S) ? labels[n * S + lane] : 0;
  const int lab_prev = __shfl_up(lab, 1);
  const bool skip  = (lab != 0) && ((lane == 0) || (lab != lab_prev));
  const float skipf = skip ? 1.0f : 0.0f;
  const int Tin = in_len[n];
  const int tl  = tgt_len[n];

  // alpha0 in linear space (no boost at t=0): only lane 0 live.
  float a0 = (lane == 0) ? __expf(base[0])   : 0.0f;
  float a1 = (lane == 0) ? __expf(base[lab]) : 0.0f;
  float logscale = 0.0f;
  int lastP = -1;

  int t0 = 1;
#pragma unroll 1
  for (int g = 0; g < NG - 1; ++g, t0 += G) {
    while (lastP < g) lastP = *vP;               // acquire spin (amortized:
    asm volatile("" ::: "memory");               //  producer runs ~6 ahead)
    float eb[G], el[G];
#pragma unroll
    for (int d = 0; d < G; ++d) {
      float2 e = *(const float2*)&E[((t0 + d) & (RS - 1)) * 128 + lane * 2];
      eb[d] = e.x; el[d] = e.y;
    }
    if (t0 + G <= Tin) {                         // fast path: all live
#pragma unroll
      for (int d = 0; d < G; ++d) {
        const float a1p = wave_shr1(a1, 0.0f);
        const float u   = a1 + a0;               // off the DPP dependency
        a0 = (a0 + a1p) * eb[d];
        a1 = fmaf(a1p, skipf, u) * el[d];
      }
    } else {                                     // tail: per-step freeze
#pragma unroll
      for (int d = 0; d < G; ++d) {
        const float a1p = wave_shr1(a1, 0.0f);
        const float u   = a1 + a0;
        const float na0 = (a0 + a1p) * eb[d];
        const float na1 = fmaf(a1p, skipf, u) * el[d];
        if (t0 + d < Tin) { a0 = na0; a1 = na1; }
      }
    }
    if (g & 1) {                                 // renorm every 16 steps
      float m = fmaxf(wavemax(fmaxf(a0, a1)), 1e-30f);
      const float inv = __builtin_amdgcn_rcpf(m);
      a0 *= inv; a1 *= inv;
      logscale -= __logf(inv);                   // log exactly what we applied
    }
    asm volatile("s_waitcnt lgkmcnt(0)" ::: "memory");  // reads done -> free
    if (lane == 0) *vC = g;
  }

  // epilogue group 63: steps t = 505..511 (row 512 produced but unused)
  {
    while (lastP < NG - 1) lastP = *vP;
    asm volatile("" ::: "memory");
#pragma unroll
    for (int d = 0; d < 7; ++d) {
      float2 e = *(const float2*)&E[((t0 + d) & (RS - 1)) * 128 + lane * 2];
      const float a1p = wave_shr1(a1, 0.0f);
      const float u   = a1 + a0;
      const float na0 = (a0 + a1p) * e.x;
      const float na1 = fmaf(a1p, skipf, u) * e.y;
      if (t0 + d < Tin) { a0 = na0; a1 = na1; }
    }
  }

  // tails: alpha[2*tl-1] (lane tl-1, odd slot), alpha[2*tl] (lane tl, even)
  const float tail1 = __shfl(a1, tl - 1);
  const float tail2 = __shfl(a0, tl);
  if (lane == 0) {
    const int live = ((Tin < T) ? Tin : T) - 1;  // boosted live steps
    float loss = -(__logf(tail1 + tail2) + logscale - BOOST * (float)live);
    if (!(loss <= 1e29f) || isnan(loss)) loss = 0.0f;  // zero_infinity
    loss_ws[n] = loss / (float)tl;
  }
}

__launch_bounds__(256)
__global__ void ctc_reduce_kernel(const float* __restrict__ loss_ws,
                                  float* __restrict__ out) {
  const int tid = threadIdx.x;
  float v = loss_ws[tid];
#pragma unroll
  for (int off = 32; off > 0; off >>= 1) v += __shfl_down(v, off);
  __shared__ float partial[4];
  if ((tid & 63) == 0) partial[tid >> 6] = v;
  __syncthreads();
  if (tid == 0) {
    float s = (partial[0] + partial[1] + partial[2] + partial[3]) / (float)N;
    if (isnan(s) || isinf(s)) s = 0.0f;          // final sanitize()
    out[0] = s;
  }
}

extern "C" void kernel_launch(void* const* d_in, const int* in_sizes, int n_in,
                              void* d_out, int out_size, void* d_ws, size_t ws_size,
                              hipStream_t stream) {
  const float* lp     = (const float*)d_in[0];   // (T, N, C) fp32
  const int*   labels = (const int*)d_in[1];     // (N, S)
  const int*   plen   = (const int*)d_in[2];     // (N,)
  const int*   tlen   = (const int*)d_in[3];     // (N,)
  float* ws  = (float*)d_ws;                     // N floats of scratch
  float* out = (float*)d_out;                    // scalar

  ctc_alpha_kernel<<<N, 128, 0, stream>>>(lp, labels, plen, tlen, ws);
  ctc_reduce_kernel<<<1, 256, 0, stream>>>(ws, out);
}

// Round 7
// 207.694 us; speedup vs baseline: 1.1793x; 1.1793x over previous
//
#include <hip/hip_runtime.h>

// CTC loss forward. logits (T,N,C) fp32 log-probs, labels (N,S) int32 in
// [1,C), prediction/target sizes (N,).
//
// One 64-lane wave per batch item n; lane i owns extended-lattice positions
// 2i (blank) and 2i+1 (label i); cross-lane dep per step = one DPP wave_shr1.
// Alpha tracked in LINEAR space (R5): add/fma/mul chain, wave-uniform renorm
// every 16 steps (DPP-max butterfly, logged into logscale), emissions exp'd
// off-chain with a +4.0/step boost, validity masks folded into emissions.
//
// R4/R5/R6 post-mortem: the scattered per-row global_load_lds gather (64
// lanes -> random columns of a 1KB row) saturates the texture unit's fill
// queue (~8-16 cache-line transactions per instruction) and caps the kernel
// at 70-105us regardless of chain cost or wave specialization; L3-resident
// replays run at identical speed (latency exonerated, throughput guilty).
// R7: stage FULL contiguous rows instead -- one width-16 global_load_lds
// (global_load_lds_dwordx4, 64 lanes x 16B = the whole 1KB row) per t-row,
// and do the label-select on the LDS side (broadcast ds_read for blank col
// 0, lane-indexed ds_read for col lab_i; ~2-way bank aliasing is free).
// Single wave, 64-row ring (64KB), issue-ahead 40, vmcnt(24) per 8-step
// group, one-group-ahead register double buffer.

constexpr int T = 512, N = 256, C = 256, S = 48;
constexpr int G = 8;                   // steps per group
constexpr int AH = 40;                 // issue-ahead rows
constexpr float BOOST = 4.0f;          // per-live-step emission boost (e^4)
static_assert((T - 1) == 63 * G + 7, "schedule hardcodes 63 groups + 7 epilogue");

__device__ __forceinline__ float wave_shr1(float v, float fill) {
  int r = __builtin_amdgcn_update_dpp(__float_as_int(fill), __float_as_int(v),
                                      0x138, 0xf, 0xf, false);  // wave_shr1
  return __int_as_float(r);
}

#define DPP_MAX(v, ctrl)                                                     \
  fmaxf(v, __int_as_float(__builtin_amdgcn_update_dpp(                       \
               __float_as_int(v), __float_as_int(v), (ctrl), 0xf, 0xf, false)))

// max over 64 lanes, wave-uniform result (alpha >= 0, old-value fallback on
// bcast-inactive lanes is safe).
__device__ __forceinline__ float wavemax(float v) {
  v = DPP_MAX(v, 0x111);               // row_shr:1
  v = DPP_MAX(v, 0x112);               // row_shr:2
  v = DPP_MAX(v, 0x114);               // row_shr:4
  v = DPP_MAX(v, 0x118);               // row_shr:8
  v = DPP_MAX(v, 0x142);               // row_bcast:15
  v = DPP_MAX(v, 0x143);               // row_bcast:31 -> lane 63 = full max
  return __int_as_float(__builtin_amdgcn_readlane(__float_as_int(v), 63));
}

// async global->LDS, 16B/lane: lane j loads g + j*16, HW writes l + j*16.
__device__ __forceinline__ void gload_lds16(const float* g, float* l) {
  __builtin_amdgcn_global_load_lds(
      (const __attribute__((address_space(1))) unsigned int*)g,
      (__attribute__((address_space(3))) unsigned int*)l, 16, 0, 0);
}

__launch_bounds__(64, 1)
__global__ void ctc_alpha_kernel(const float* __restrict__ lp,
                                 const int*  __restrict__ labels,
                                 const int*  __restrict__ in_len,
                                 const int*  __restrict__ tgt_len,
                                 float* __restrict__ loss_ws) {
  __shared__ float ring[64 * 256];     // 64 rows x 1KB = 64 KB

  const int n    = blockIdx.x;
  const int lane = threadIdx.x;

  const int lab      = (lane < S) ? labels[n * S + lane] : 0;
  const int lab_prev = __shfl_up(lab, 1);
  const bool skip   = (lab != 0) && ((lane == 0) || (lab != lab_prev));
  const float skipf = skip ? 1.0f : 0.0f;
  const bool valid0 = (lane <= S);     // pos 2i     in [0, 2S]
  const bool valid1 = (lane <  S);     // pos 2i + 1 in [0, 2S]
  const int Tin = in_len[n];
  const int tl  = tgt_len[n];

  const size_t tstride = (size_t)N * C;          // floats per t-row
  const float* nbase  = lp + (size_t)n * C;      // lp[0][n][:]
  const float* gbase  = nbase + lane * 4;        // per-lane 16B chunk

  // stage row `row` (clamped address; clamped slots are never consumed)
  auto issue = [&](int row) {
    const int rr = (row < T) ? row : (T - 1);
    gload_lds16(gbase + (size_t)rr * tstride, &ring[(row & 63) * 256]);
  };

  // LDS-side select + exp + mask for row `row` (row must be resident)
  auto fetch = [&](int row, float& eb, float& el) {
    const int s = (row & 63) * 256;
    const float b = ring[s];                     // broadcast (col 0)
    const float l = ring[s + lab];               // lane-indexed (col lab)
    eb = valid0 ? __expf(b + BOOST) : 0.0f;
    el = valid1 ? __expf(l + BOOST) : 0.0f;
  };

  // alpha0 in linear space (no boost at t=0): only lane 0 live.
  float a0 = (lane == 0) ? __expf(nbase[0])   : 0.0f;
  float a1 = (lane == 0) ? __expf(nbase[lab]) : 0.0f;
  float logscale = 0.0f;

  // Prologue: rows 1..AH in flight.
#pragma unroll
  for (int r = 1; r <= AH; ++r) issue(r);

  // rows 1..8 resident (40 issued, wait until <=32 outstanding -> 8 retired)
  asm volatile("s_waitcnt vmcnt(32)" ::: "memory");
  float cb[G], cl[G];
#pragma unroll
  for (int d = 0; d < G; ++d) fetch(1 + d, cb[d], cl[d]);

  int t0 = 1;
#pragma unroll 1
  for (int g = 0; g < 63; ++g, t0 += G) {
    // issued through t0+39; wait <=24 outstanding -> rows <= t0+15 resident
    asm volatile("s_waitcnt vmcnt(24)" ::: "memory");
    float nb[G], nl[G];
#pragma unroll
    for (int d = 0; d < G; ++d) fetch(t0 + G + d, nb[d], nl[d]);

    if (t0 + G <= Tin) {                         // fast path: all 8 live
#pragma unroll
      for (int d = 0; d < G; ++d) {
        const float a1p = wave_shr1(a1, 0.0f);
        const float u   = a1 + a0;               // off the DPP dependency
        a0 = (a0 + a1p) * cb[d];
        a1 = fmaf(a1p, skipf, u) * cl[d];
      }
    } else {                                     // tail: per-step freeze
#pragma unroll
      for (int d = 0; d < G; ++d) {
        const float a1p = wave_shr1(a1, 0.0f);
        const float u   = a1 + a0;
        const float na0 = (a0 + a1p) * cb[d];
        const float na1 = fmaf(a1p, skipf, u) * cl[d];
        if (t0 + d < Tin) { a0 = na0; a1 = na1; }
      }
    }
    if (g & 1) {                                 // renorm every 16 steps
      float m = fmaxf(wavemax(fmaxf(a0, a1)), 1e-30f);
      const float inv = __builtin_amdgcn_rcpf(m);
      a0 *= inv; a1 *= inv;
      logscale -= __logf(inv);                   // log exactly what we applied
    }
#pragma unroll
    for (int d = 0; d < G; ++d) issue(t0 + AH + d);
#pragma unroll
    for (int d = 0; d < G; ++d) { cb[d] = nb[d]; cl[d] = nl[d]; }
  }

  // Epilogue: t = 505..511 (cb[7] = clamped row 512, never used).
#pragma unroll
  for (int d = 0; d < 7; ++d) {
    const float a1p = wave_shr1(a1, 0.0f);
    const float u   = a1 + a0;
    const float na0 = (a0 + a1p) * cb[d];
    const float na1 = fmaf(a1p, skipf, u) * cl[d];
    if (t0 + d < Tin) { a0 = na0; a1 = na1; }
  }

  // tails: alpha[2*tl-1] (lane tl-1, odd slot), alpha[2*tl] (lane tl, even)
  const float tail1 = __shfl(a1, tl - 1);
  const float tail2 = __shfl(a0, tl);
  if (lane == 0) {
    const int live = ((Tin < T) ? Tin : T) - 1;  // boosted live steps
    float loss = -(__logf(tail1 + tail2) + logscale - BOOST * (float)live);
    if (!(loss <= 1e29f) || isnan(loss)) loss = 0.0f;  // zero_infinity
    loss_ws[n] = loss / (float)tl;
  }
}

__launch_bounds__(256)
__global__ void ctc_reduce_kernel(const float* __restrict__ loss_ws,
                                  float* __restrict__ out) {
  const int tid = threadIdx.x;
  float v = loss_ws[tid];
#pragma unroll
  for (int off = 32; off > 0; off >>= 1) v += __shfl_down(v, off);
  __shared__ float partial[4];
  if ((tid & 63) == 0) partial[tid >> 6] = v;
  __syncthreads();
  if (tid == 0) {
    float s = (partial[0] + partial[1] + partial[2] + partial[3]) / (float)N;
    if (isnan(s) || isinf(s)) s = 0.0f;          // final sanitize()
    out[0] = s;
  }
}

extern "C" void kernel_launch(void* const* d_in, const int* in_sizes, int n_in,
                              void* d_out, int out_size, void* d_ws, size_t ws_size,
                              hipStream_t stream) {
  const float* lp     = (const float*)d_in[0];   // (T, N, C) fp32
  const int*   labels = (const int*)d_in[1];     // (N, S)
  const int*   plen   = (const int*)d_in[2];     // (N,)
  const int*   tlen   = (const int*)d_in[3];     // (N,)
  float* ws  = (float*)d_ws;                     // N floats of scratch
  float* out = (float*)d_out;                    // scalar

  ctc_alpha_kernel<<<N, 64, 0, stream>>>(lp, labels, plen, tlen, ws);
  ctc_reduce_kernel<<<1, 256, 0, stream>>>(ws, out);
}